// Round 1
// baseline (56.913 us; speedup 1.0000x reference)
//
#include <hip/hip_runtime.h>
#include <hip/hip_bf16.h>

// LoRA conv experts, algebraically collapsed:
//   out = sum_e p_e * Conv3x1(w_out_e) ( Conv1x3(w_in_e) (x) )
// Both convs are linear => fold experts into ONE rank-64 separable pair:
//   W1[(e,r)][kx*256+c] = p_e * w_in[e,r,c,0,kx]    (64 x 768)
//   W2[o][ky*64+(e,r)]  = w_out[e,o,r,ky,0]         (256 x 192)
//   h = conv1x3(x, W1)  [16,64,64,64]; out = conv3x1(h, W2)

typedef __bf16 bf16x8 __attribute__((ext_vector_type(8)));
typedef float  f32x4  __attribute__((ext_vector_type(4)));
typedef unsigned short us8 __attribute__((ext_vector_type(8)));

#define CIN_  256
#define COUT_ 256
#define M1    64      // E*R
#define K1    768     // 3*CIN
#define K2    192     // 3*M1

static __device__ __forceinline__ unsigned short f2bf(float f) {
    union { float f; unsigned u; } v; v.f = f;
    unsigned r = v.u + 0x7FFFu + ((v.u >> 16) & 1u);
    return (unsigned short)(r >> 16);
}

// ---------------- weight prep: fold probs, reorder, cast to bf16 -------------
__global__ void prep_weights(const float* __restrict__ probs,
                             const float* __restrict__ w_in,
                             const float* __restrict__ w_out,
                             unsigned short* __restrict__ W1,
                             unsigned short* __restrict__ W2) {
    int idx = blockIdx.x * blockDim.x + threadIdx.x;
    if (idx < M1 * K1) {
        // W1[er][kx*256+c] = p_e * w_in[(er*256+c)*3 + kx]
        int er = idx / K1, rem = idx % K1;
        int kx = rem / CIN_, c = rem % CIN_;
        int e = er >> 3;
        float v = probs[e] * w_in[(er * CIN_ + c) * 3 + kx];
        W1[idx] = f2bf(v);
    } else {
        int i2 = idx - M1 * K1;
        if (i2 < COUT_ * K2) {
            // W2[o][ky*64+er] = w_out[((e*256+o)*8+r)*3 + ky]
            int o = i2 / K2, rem = i2 % K2;
            int ky = rem / M1, er = rem % M1;
            int e = er >> 3, r = er & 7;
            float v = w_out[((e * COUT_ + o) * 8 + r) * 3 + ky];
            W2[i2] = f2bf(v);
        }
    }
}

// ---------------- conv 1x3: x[16,256,64,64] f32 -> h[16,64,64,64] bf16 -------
// One block per (b,y). GEMM [64 x 768] * [768 x 64].
// LDS x-tile stored transposed [ns][c] (ns = spatial+1 with zero halo) so each
// B-fragment is one ds_read_b128 (K contiguous per lane).
#define XS_STRIDE 40  // 32 + 8 pad (80B rows, 16B-aligned, spreads b128 reads)
__global__ __launch_bounds__(256)
void conv_in_kernel(const float* __restrict__ x,
                    const unsigned short* __restrict__ W1,
                    unsigned short* __restrict__ h) {
    __shared__ unsigned short xs[66 * XS_STRIDE];
    const int bid  = blockIdx.x;
    const int b    = bid >> 6, y = bid & 63;
    const int tid  = threadIdx.x;
    const int lane = tid & 63;
    const int wave = tid >> 6;       // 4 waves; wave = m-tile
    const int g    = lane >> 4;      // 0..3 (K sub-group)
    const int lr   = lane & 15;

    if (tid < 64) {  // zero halo columns (actual n = -1 and 64)
        int ns = (tid < 32) ? 0 : 65;
        xs[ns * XS_STRIDE + (tid & 31)] = 0;
    }

    f32x4 acc[4];
    #pragma unroll
    for (int i = 0; i < 4; ++i) acc[i] = (f32x4){0.f, 0.f, 0.f, 0.f};

    // staging map: c_l = tid&31, n0 = (tid>>5)*8  (lanes l and l+32 cover 64B)
    const int c_l = tid & 31;
    const int n0  = (tid >> 5) << 3;
    const float* xrow = x + (((b * CIN_ + c_l) * 64 + y) * 64 + n0);

    for (int cc = 0; cc < 8; ++cc) {
        __syncthreads();
        float4 v0 = *(const float4*)(xrow + cc * 32 * 4096);
        float4 v1 = *(const float4*)(xrow + cc * 32 * 4096 + 4);
        unsigned short* dst = &xs[(n0 + 1) * XS_STRIDE + c_l];
        dst[0 * XS_STRIDE] = f2bf(v0.x);
        dst[1 * XS_STRIDE] = f2bf(v0.y);
        dst[2 * XS_STRIDE] = f2bf(v0.z);
        dst[3 * XS_STRIDE] = f2bf(v0.w);
        dst[4 * XS_STRIDE] = f2bf(v1.x);
        dst[5 * XS_STRIDE] = f2bf(v1.y);
        dst[6 * XS_STRIDE] = f2bf(v1.z);
        dst[7 * XS_STRIDE] = f2bf(v1.w);
        __syncthreads();
        #pragma unroll
        for (int kx = 0; kx < 3; ++kx) {
            bf16x8 afrag = *(const bf16x8*)(W1 + (wave * 16 + lr) * K1 +
                                            kx * CIN_ + cc * 32 + g * 8);
            #pragma unroll
            for (int nt = 0; nt < 4; ++nt) {
                int ns = nt * 16 + lr + kx;  // = n + kx (stored with +1 halo shift)
                bf16x8 bfrag = *(const bf16x8*)&xs[ns * XS_STRIDE + g * 8];
                acc[nt] = __builtin_amdgcn_mfma_f32_16x16x32_bf16(afrag, bfrag,
                                                                  acc[nt], 0, 0, 0);
            }
        }
    }
    // D layout: row = g*4+reg, col = lr  -> h[b, wave*16+row, y, nt*16+lr]
    #pragma unroll
    for (int nt = 0; nt < 4; ++nt) {
        int n = nt * 16 + lr;
        #pragma unroll
        for (int r2 = 0; r2 < 4; ++r2) {
            int m = wave * 16 + g * 4 + r2;
            h[((b * M1 + m) * 64 + y) * 64 + n] = f2bf(acc[nt][r2]);
        }
    }
}

// ---------------- conv 3x1: h[16,64,64,64] bf16 -> out[16,256,64,64] f32 -----
// One block per (b,y). GEMM [256 x 192] * [192 x 64].
// LDS h-tile transposed [xr][k=ky*64+m], k bits 3-4 XOR-swizzled by (xr>>4)&3
// so transpose writes and b128 reads are both ~conflict-free.
#define HS_STRIDE 200  // 192 + 8 pad (400B rows, 16B-aligned)
__global__ __launch_bounds__(256)
void conv_out_kernel(const unsigned short* __restrict__ h,
                     const unsigned short* __restrict__ W2,
                     float* __restrict__ out) {
    __shared__ unsigned short hs[64 * HS_STRIDE];
    const int bid  = blockIdx.x;
    const int b    = bid >> 6, y = bid & 63;
    const int tid  = threadIdx.x;
    const int lane = tid & 63;
    const int wave = tid >> 6;       // wave -> o-tiles [wave*4, wave*4+4)
    const int g    = lane >> 4;
    const int lr   = lane & 15;

    // staging map: m = tid>>2, x0 = (tid&3)*16 (4 lanes cover one 128B h-row)
    const int ms = tid >> 2;
    const int x0 = (tid & 3) << 4;
    const int sw = (tid & 3) << 3;   // = ((xr>>4)&3)<<3 for this thread's xr
    #pragma unroll
    for (int ky = 0; ky < 3; ++ky) {
        int ys = y + ky - 1;
        int kcol = ky * M1 + ms;
        int kswz = kcol ^ sw;
        if (ys >= 0 && ys < 64) {
            const unsigned short* src = h + ((b * M1 + ms) * 64 + ys) * 64 + x0;
            us8 v0 = *(const us8*)(src);
            us8 v1 = *(const us8*)(src + 8);
            #pragma unroll
            for (int i = 0; i < 8; ++i)
                hs[(x0 + i) * HS_STRIDE + kswz] = v0[i];
            #pragma unroll
            for (int i = 0; i < 8; ++i)
                hs[(x0 + 8 + i) * HS_STRIDE + kswz] = v1[i];
        } else {
            #pragma unroll
            for (int i = 0; i < 16; ++i)
                hs[(x0 + i) * HS_STRIDE + kswz] = 0;
        }
    }
    __syncthreads();

    f32x4 acc[4][4];
    #pragma unroll
    for (int ot = 0; ot < 4; ++ot)
        #pragma unroll
        for (int nt = 0; nt < 4; ++nt) acc[ot][nt] = (f32x4){0.f, 0.f, 0.f, 0.f};

    #pragma unroll
    for (int kc = 0; kc < 6; ++kc) {
        bf16x8 bfrag[4];
        #pragma unroll
        for (int nt = 0; nt < 4; ++nt) {
            int xr = nt * 16 + lr;   // xr>>4 == nt
            bfrag[nt] = *(const bf16x8*)&hs[xr * HS_STRIDE + kc * 32 + ((g ^ nt) << 3)];
        }
        #pragma unroll
        for (int ot = 0; ot < 4; ++ot) {
            bf16x8 afrag = *(const bf16x8*)(W2 + ((wave * 4 + ot) * 16 + lr) * K2 +
                                            kc * 32 + g * 8);
            #pragma unroll
            for (int nt = 0; nt < 4; ++nt)
                acc[ot][nt] = __builtin_amdgcn_mfma_f32_16x16x32_bf16(afrag, bfrag[nt],
                                                                      acc[ot][nt], 0, 0, 0);
        }
    }

    #pragma unroll
    for (int ot = 0; ot < 4; ++ot) {
        #pragma unroll
        for (int r2 = 0; r2 < 4; ++r2) {
            int o = (wave * 4 + ot) * 16 + g * 4 + r2;
            float* orow = out + ((b * COUT_ + o) * 64 + y) * 64;
            #pragma unroll
            for (int nt = 0; nt < 4; ++nt)
                orow[nt * 16 + lr] = acc[ot][nt][r2];
        }
    }
}

extern "C" void kernel_launch(void* const* d_in, const int* in_sizes, int n_in,
                              void* d_out, int out_size, void* d_ws, size_t ws_size,
                              hipStream_t stream) {
    const float* x     = (const float*)d_in[0];   // [16,256,64,64]
    const float* probs = (const float*)d_in[1];   // [8]
    const float* w_in  = (const float*)d_in[2];   // [8,8,256,1,3]
    const float* w_out = (const float*)d_in[3];   // [8,256,8,3,1]
    float* out = (float*)d_out;                   // [16,256,64,64] f32

    unsigned short* W1 = (unsigned short*)d_ws;          // 64*768 bf16
    unsigned short* W2 = W1 + M1 * K1;                   // 256*192 bf16
    unsigned short* h  = W2 + COUT_ * K2;                // 16*64*64*64 bf16 (8MB)

    prep_weights<<<(M1 * K1 + COUT_ * K2 + 255) / 256, 256, 0, stream>>>(
        probs, w_in, w_out, W1, W2);
    conv_in_kernel<<<16 * 64, 256, 0, stream>>>(x, W1, h);
    conv_out_kernel<<<16 * 64, 256, 0, stream>>>(h, W2, out);
}